// Round 4
// baseline (184.944 us; speedup 1.0000x reference)
//
#include <hip/hip_runtime.h>

// TripletAngularMarginLoss: bs=16384, d=64 (== number of classes)
// out = mean(relu(0.5 + ap - an)) + mean(relu(0.8-ap)) + mean(relu(an-0.4)) + CE
// ap[i] = min_{t[j]==t[i]} cos(x_i,x_j), an[i] = max_{t[j]!=t[i]} cos(x_i,x_j)
//
// R2: masked epilogue was VALU-bound -> class-sort rows, pure-negative fast path.
// R3: (a) single-block sort cost ~60us -> parallel 4-stage sort;
//     (b) mine latency-bound (MfmaUtil 14/VALU 37/occ 38) -> 64-col j-tiles,
//         batched loads, zero-C MFMA, strength-reduced addressing.

#define N_ROWS 16384
#define N_DIM 64

typedef __attribute__((ext_vector_type(8))) short bf16x8;
typedef __attribute__((ext_vector_type(4))) float f32x4;

__device__ inline unsigned short f2bf(float f) {
  unsigned u = __float_as_uint(f);
  unsigned r = u + 0x7fffu + ((u >> 16) & 1u);   // round-to-nearest-even
  return (unsigned short)(r >> 16);
}

// order-preserving float->uint encoding for atomicMin/atomicMax
__device__ inline unsigned enc_key(float f) {
  unsigned u = __float_as_uint(f);
  return (u & 0x80000000u) ? ~u : (u | 0x80000000u);
}
__device__ inline float dec_key(unsigned k) {
  unsigned u = (k & 0x80000000u) ? (k ^ 0x80000000u) : ~k;
  return __uint_as_float(u);
}

// ---------------- Sort stage 0: init keys + hist (grid-wide) ----------------
__global__ void init_kernel(unsigned* __restrict__ mp_key, unsigned* __restrict__ mn_key,
                            int* __restrict__ hist) {
  const int i = blockIdx.x * 256 + threadIdx.x;   // grid 64x256 = 16384
  mp_key[i] = 0xFFFFFFFFu;                        // +inf key for min
  mn_key[i] = 0u;                                 // -inf key for max
  if (blockIdx.x == 0 && threadIdx.x < 64) hist[threadIdx.x] = 0;
}

// ---------------- Sort stage 1: class histogram (16 blocks) -----------------
__global__ void hist_kernel(const int* __restrict__ tgt, int* __restrict__ hist) {
  __shared__ int h[64];
  if (threadIdx.x < 64) h[threadIdx.x] = 0;
  __syncthreads();
  atomicAdd(&h[tgt[blockIdx.x * 1024 + threadIdx.x]], 1);
  __syncthreads();
  if (threadIdx.x < 64) atomicAdd(&hist[threadIdx.x], h[threadIdx.x]);
}

// ---------------- Sort stage 2: exclusive scan (1 wave) ---------------------
__global__ void scan_kernel(const int* __restrict__ hist, int* __restrict__ class_start,
                            int* __restrict__ cursor) {
  const int tid = threadIdx.x;     // 64 threads
  const int h = hist[tid];
  int s = h;
#pragma unroll
  for (int d = 1; d < 64; d <<= 1) {
    int t = __shfl_up(s, d, 64);
    if (tid >= d) s += t;
  }
  class_start[tid] = s - h;
  cursor[tid]      = s - h;
  if (tid == 63) class_start[64] = s;
}

// ---------------- Sort stage 3: scatter positions (16 blocks) ---------------
__global__ void scatter_kernel(const int* __restrict__ tgt, int* __restrict__ cursor,
                               int* __restrict__ perm, int* __restrict__ ts) {
  const int r = blockIdx.x * 1024 + threadIdx.x;
  const int c = tgt[r];
  const int pos = atomicAdd(&cursor[c], 1);
  perm[r] = pos;
  ts[pos] = c;
}

// ---------------- Prep: normalize, CE term, bf16 row to sorted slot ---------
__global__ void prep_kernel(const float* __restrict__ x, const int* __restrict__ tgt,
                            const int* __restrict__ perm,
                            unsigned short* __restrict__ xs, float* __restrict__ ce_row) {
  const int row  = blockIdx.x * 4 + (threadIdx.x >> 6);
  const int lane = threadIdx.x & 63;
  float v  = x[row * N_DIM + lane];
  float ss = v * v;
#pragma unroll
  for (int s = 1; s < 64; s <<= 1) ss += __shfl_xor(ss, s, 64);
  float xn = v * rsqrtf(ss);
  xs[perm[row] * N_DIM + lane] = f2bf(xn);

  float mx = xn;
#pragma unroll
  for (int s = 1; s < 64; s <<= 1) mx = fmaxf(mx, __shfl_xor(mx, s, 64));
  float e  = __expf(xn - mx);
  float se = e;
#pragma unroll
  for (int s = 1; s < 64; s <<= 1) se += __shfl_xor(se, s, 64);
  float lse = mx + __logf(se);
  int   t   = tgt[row];
  float xt  = __shfl(xn, t, 64);
  if (lane == 0) ce_row[row] = lse - xt;
}

// ---------------- Mine: MFMA similarity + hard mining (sorted layout) -------
// grid = 64 i-blocks * 16 j-splits = 1024 blocks of 256 threads (4 waves).
// Wave: 64 sorted i-rows register-resident (A), sweeps 1024 cols in 64-col
// iterations: 8 batched 16B loads up-front, then 4 tc-groups of 2 MFMAs.
__global__ void __launch_bounds__(256, 3)
mine_kernel(const unsigned short* __restrict__ xs, const int* __restrict__ ts,
            const int* __restrict__ class_start,
            unsigned* __restrict__ mp_key, unsigned* __restrict__ mn_key) {
  const int lane    = threadIdx.x & 63;
  const int wv      = threadIdx.x >> 6;
  const int iblk    = blockIdx.x >> 4;
  const int jspl    = blockIdx.x & 15;
  const int rowbase = iblk * 256 + wv * 64;
  const int m = lane & 15, q = lane >> 4;

  // A fragments: lane holds row (rowbase+tr*16+m), k = q*8..q*8+7 (+32)
  bf16x8 a[4][2];
#pragma unroll
  for (int tr = 0; tr < 4; ++tr) {
    const unsigned short* p = xs + (rowbase + tr * 16 + m) * N_DIM + q * 8;
    a[tr][0] = *(const bf16x8*)(p);
    a[tr][1] = *(const bf16x8*)(p + 32);
  }
  // classes of this lane's C/D rows (row = tr*16 + q*4 + r), slow path use
  int ti[16];
#pragma unroll
  for (int tr = 0; tr < 4; ++tr)
#pragma unroll
    for (int r = 0; r < 4; ++r)
      ti[tr * 4 + r] = ts[rowbase + tr * 16 + q * 4 + r];

  // positive-column interval for ALL rows of this wave (rows sorted by class)
  const int lo = class_start[ts[rowbase]];
  const int hi = class_start[ts[rowbase + 63] + 1];

  float mp[16], mn[16];
#pragma unroll
  for (int k = 0; k < 16; ++k) { mp[k] = __builtin_inff(); mn[k] = -__builtin_inff(); }

  const int jbase = jspl * 1024;
  const unsigned short* pw = xs + jbase * N_DIM;   // wave-uniform base
  const int loff = m * N_DIM + q * 8;              // per-lane offset (shorts)
  const f32x4 fz = {0.f, 0.f, 0.f, 0.f};

  for (int it = 0; it < 16; ++it) {
    // batch all 8 fragment loads for this 64-col tile
    const unsigned short* p = pw + it * (64 * N_DIM) + loff;
    bf16x8 b[4][2];
#pragma unroll
    for (int tc = 0; tc < 4; ++tc) {
      b[tc][0] = *(const bf16x8*)(p + tc * (16 * N_DIM));
      b[tc][1] = *(const bf16x8*)(p + tc * (16 * N_DIM) + 32);
    }
    const int jb0 = jbase + it * 64;
#pragma unroll
    for (int tc = 0; tc < 4; ++tc) {
      const int jb = jb0 + tc * 16;
      if ((jb < hi) && (jb + 16 > lo)) {     // wave-uniform slow path (rare)
        const int ctj = ts[jb + m];          // class of this lane's column
#pragma unroll
        for (int tr = 0; tr < 4; ++tr) {
          f32x4 acc = __builtin_amdgcn_mfma_f32_16x16x32_bf16(a[tr][0], b[tc][0], fz, 0, 0, 0);
          acc = __builtin_amdgcn_mfma_f32_16x16x32_bf16(a[tr][1], b[tc][1], acc, 0, 0, 0);
#pragma unroll
          for (int r = 0; r < 4; ++r) {
            const bool  pos = (ctj == ti[tr * 4 + r]);
            const float d   = acc[r];
            mp[tr * 4 + r] = fminf(mp[tr * 4 + r], pos ? d : __builtin_inff());
            mn[tr * 4 + r] = fmaxf(mn[tr * 4 + r], pos ? -__builtin_inff() : d);
          }
        }
      } else {                               // pure-negative fast path
#pragma unroll
        for (int tr = 0; tr < 4; ++tr) {
          f32x4 acc = __builtin_amdgcn_mfma_f32_16x16x32_bf16(a[tr][0], b[tc][0], fz, 0, 0, 0);
          acc = __builtin_amdgcn_mfma_f32_16x16x32_bf16(a[tr][1], b[tc][1], acc, 0, 0, 0);
#pragma unroll
          for (int r = 0; r < 4; ++r)
            mn[tr * 4 + r] = fmaxf(mn[tr * 4 + r], acc[r]);
        }
      }
    }
  }

  // reduce across the 16 m-lanes inside each q-group
#pragma unroll
  for (int s = 1; s < 16; s <<= 1) {
#pragma unroll
    for (int k = 0; k < 16; ++k) {
      mp[k] = fminf(mp[k], __shfl_xor(mp[k], s, 64));
      mn[k] = fmaxf(mn[k], __shfl_xor(mn[k], s, 64));
    }
  }
  if (m == 0) {
#pragma unroll
    for (int tr = 0; tr < 4; ++tr)
#pragma unroll
      for (int r = 0; r < 4; ++r) {
        const int row = rowbase + tr * 16 + q * 4 + r;
        atomicMin(&mp_key[row], enc_key(mp[tr * 4 + r]));
        atomicMax(&mn_key[row], enc_key(mn[tr * 4 + r]));
      }
  }
}

// ---------------- Finalize: reduce all terms (1024 threads) -----------------
__global__ void finalize_kernel(const unsigned* __restrict__ mp_key, const unsigned* __restrict__ mn_key,
                                const float* __restrict__ ce_row, float* __restrict__ out) {
  __shared__ float red[4][16];
  float s1 = 0.f, s2 = 0.f, s3 = 0.f, s4 = 0.f;
  for (int r = threadIdx.x; r < N_ROWS; r += 1024) {
    float ap = dec_key(mp_key[r]);
    float an = dec_key(mn_key[r]);
    s1 += fmaxf(0.5f + ap - an, 0.f);
    s2 += fmaxf(0.8f - ap, 0.f);
    s3 += fmaxf(an - 0.4f, 0.f);
    s4 += ce_row[r];
  }
#pragma unroll
  for (int s = 1; s < 64; s <<= 1) {
    s1 += __shfl_xor(s1, s, 64);
    s2 += __shfl_xor(s2, s, 64);
    s3 += __shfl_xor(s3, s, 64);
    s4 += __shfl_xor(s4, s, 64);
  }
  const int wv = threadIdx.x >> 6;
  if ((threadIdx.x & 63) == 0) {
    red[0][wv] = s1; red[1][wv] = s2; red[2][wv] = s3; red[3][wv] = s4;
  }
  __syncthreads();
  if (threadIdx.x == 0) {
    float t = 0.f;
#pragma unroll
    for (int c = 0; c < 4; ++c)
#pragma unroll
      for (int w = 0; w < 16; ++w) t += red[c][w];
    out[0] = t * (1.0f / N_ROWS);
  }
}

extern "C" void kernel_launch(void* const* d_in, const int* in_sizes, int n_in,
                              void* d_out, int out_size, void* d_ws, size_t ws_size,
                              hipStream_t stream) {
  const float* x   = (const float*)d_in[0];
  const int*   tgt = (const int*)d_in[1];
  char* ws = (char*)d_ws;

  unsigned short* xs     = (unsigned short*)ws;                           // 2 MB sorted bf16
  unsigned*       mp_key = (unsigned*)(ws + (2u << 20));                  // 64 KB
  unsigned*       mn_key = (unsigned*)(ws + (2u << 20) + (64u << 10));    // 64 KB
  float*          ce_row = (float*)(ws + (2u << 20) + (128u << 10));      // 64 KB
  int*            perm   = (int*)(ws + (2u << 20) + (192u << 10));        // 64 KB
  int*            ts     = (int*)(ws + (2u << 20) + (256u << 10));        // 64 KB
  int*            cstart = (int*)(ws + (2u << 20) + (320u << 10));        // 65*4 B
  int*            hist   = (int*)(ws + (2u << 20) + (321u << 10));        // 64*4 B
  int*            cursor = (int*)(ws + (2u << 20) + (322u << 10));        // 64*4 B
  float*          out    = (float*)d_out;

  init_kernel<<<64, 256, 0, stream>>>(mp_key, mn_key, hist);
  hist_kernel<<<16, 1024, 0, stream>>>(tgt, hist);
  scan_kernel<<<1, 64, 0, stream>>>(hist, cstart, cursor);
  scatter_kernel<<<16, 1024, 0, stream>>>(tgt, cursor, perm, ts);
  prep_kernel<<<N_ROWS / 4, 256, 0, stream>>>(x, tgt, perm, xs, ce_row);
  mine_kernel<<<64 * 16, 256, 0, stream>>>(xs, ts, cstart, mp_key, mn_key);
  finalize_kernel<<<1, 1024, 0, stream>>>(mp_key, mn_key, ce_row, out);
}